// Round 8
// baseline (433.889 us; speedup 1.0000x reference)
//
// Round 8: trace at 2 blocks/CU — 512 blocks x 8 real rows (+8 zero pad rows
// in the MFMA M-dim), R6 inner loop, q<2 guards on reductions. Staggered
// blocks fill each other's barrier-drain windows. Encoder unchanged (R7).

#include <hip/hip_runtime.h>
#include <math.h>

typedef short bf8 __attribute__((ext_vector_type(8)));   // 8 bf16 = 4 VGPR
typedef float f32x4 __attribute__((ext_vector_type(4))); // MFMA acc

namespace {

constexpr float H_STEP = 1.0f / 15.0f;

__device__ inline short f2bf(float f) {  // RNE f32 -> bf16
  unsigned u = __float_as_uint(f);
  u += 0x7fffu + ((u >> 16) & 1u);
  return (short)(u >> 16);
}

__device__ inline float fast_tanh(float x) {
  const float ax = fabsf(x);
  const float e = __expf(-2.0f * ax);
  const float t = (1.0f - e) * __builtin_amdgcn_rcpf(1.0f + e);
  return copysignf(t, x);
}

// 1 - tanh(x)^2 = 4 e / (1+e)^2, e = exp(-2|x|)
__device__ inline float sech2(float x) {
  const float e = __expf(-2.0f * fabsf(x));
  const float r = __builtin_amdgcn_rcpf(1.0f + e);
  return 4.0f * e * r * r;
}

// sum over each 16-lane group via DPP row_ror 1/2/4/8 (VALU-rate butterfly)
template <int CTRL>
__device__ inline float dppadd(float v) {
  return v + __int_as_float(__builtin_amdgcn_update_dpp(
                 0, __float_as_int(v), CTRL, 0xF, 0xF, true));
}
__device__ inline float red16(float v) {
  v = dppadd<0x121>(v);
  v = dppadd<0x122>(v);
  v = dppadd<0x124>(v);
  v = dppadd<0x128>(v);
  return v;
}

// async global->LDS, 16B per lane. LDS dest = wave-uniform base + lane*16.
__device__ inline void async16(const void* g, void* l) {
  __builtin_amdgcn_global_load_lds((__attribute__((address_space(1))) void*)g,
                                   (__attribute__((address_space(3))) void*)l,
                                   16, 0, 0);
}

// ---------------- one-shot prep: inputs + all weight converts ----------------
__global__ __launch_bounds__(256) void prep_all(
    const float* __restrict__ xs, const float* __restrict__ xe,
    const float* __restrict__ W1, const float* __restrict__ W2,
    const float* __restrict__ Ww1, const float* __restrict__ Ww2,
    const float* __restrict__ Wp1, const float* __restrict__ wp2,
    short* __restrict__ XSb, short* __restrict__ W1T, short* __restrict__ W2T,
    short* __restrict__ Ww1T, short* __restrict__ Ww2T,
    short* __restrict__ WpT, short* __restrict__ Wp1s) {
  __shared__ float tile[32][33];
  const int id = blockIdx.x;
  if (id < 2048) {
    const long n = (long)8192 * 2048, half = n >> 1;
    long i = ((long)id * 256 + threadIdx.x) * 4;
    const long stride = (long)2048 * 1024;
    for (; i < n; i += stride) {
      const float* s = (i < half) ? (xs + i) : (xe + (i - half));
      const float4 f = *(const float4*)s;
      ushort4 o;
      o.x = (unsigned short)f2bf(f.x);
      o.y = (unsigned short)f2bf(f.y);
      o.z = (unsigned short)f2bf(f.z);
      o.w = (unsigned short)f2bf(f.w);
      *(ushort4*)(XSb + i) = o;
    }
    return;
  }
  const int tr = threadIdx.x >> 5, tc = threadIdx.x & 31;
  const float* src;
  short* dst;
  int K, N, kt, nt;
  if (id < 4096) {
    src = W1; dst = W1T; K = 2048; N = 1024; kt = (id - 2048) >> 5; nt = (id - 2048) & 31;
  } else if (id < 4352) {
    src = W2; dst = W2T; K = 1024; N = 256; kt = (id - 4096) >> 3; nt = (id - 4096) & 7;
  } else if (id < 4416) {
    src = Ww1; dst = Ww1T; K = 256; N = 256; kt = (id - 4352) >> 3; nt = (id - 4352) & 7;
  } else if (id < 4480) {
    src = Ww2; dst = Ww2T; K = 256; N = 256; kt = (id - 4416) >> 3; nt = (id - 4416) & 7;
  } else if (id < 4544) {
    src = Wp1; dst = WpT; K = 256; N = 256; kt = (id - 4480) >> 3; nt = (id - 4480) & 7;
  } else {  // wp2-scaled row-major copy
    const int lid = id - 4544;
    const int k0 = (lid >> 3) * 32, n0 = (lid & 7) * 32;
#pragma unroll
    for (int i = 0; i < 32; i += 8) {
      const size_t o = (size_t)(k0 + tr + i) * 256 + n0 + tc;
      Wp1s[o] = f2bf(Wp1[o] * wp2[n0 + tc]);
    }
    return;
  }
  const int k0 = kt * 32, n0 = nt * 32;
#pragma unroll
  for (int i = 0; i < 32; i += 8)
    tile[tr + i][tc] = src[(size_t)(k0 + tr + i) * N + n0 + tc];
  __syncthreads();
#pragma unroll
  for (int i = 0; i < 32; i += 8)
    dst[(size_t)(n0 + tr + i) * K + k0 + tc] = f2bf(tile[tc][tr + i]);
}

// ---------------- bf16 TN GEMMs, global_load_lds staging ----------------

// 128x128 tile, BK=64, tanh->bf16 epilogue (encoder L1)
__global__ __launch_bounds__(256) void gemm128_tanh(
    const short* __restrict__ A, const short* __restrict__ Bt,
    const float* __restrict__ bias, short* __restrict__ Cb, int M, int N,
    int K) {
  __shared__ __align__(16) short As[2 * 128 * 32];
  __shared__ __align__(16) short Bs[2 * 128 * 32];
  const int tid = threadIdx.x;
  const int w = tid >> 6, lane = tid & 63, q = lane >> 4, l15 = lane & 15;
  const int wm = (w >> 1) * 64, wn = (w & 1) * 64;
  const int m0 = blockIdx.y * 128, n0 = blockIdx.x * 128;
  const f32x4 fzero = {0.0f, 0.0f, 0.0f, 0.0f};
  f32x4 acc[4][4];
#pragma unroll
  for (int mt = 0; mt < 4; ++mt)
#pragma unroll
    for (int nt = 0; nt < 4; ++nt) acc[mt][nt] = fzero;

  for (int k0 = 0; k0 < K; k0 += 64) {
#pragma unroll
    for (int kcb = 0; kcb < 2; ++kcb)
#pragma unroll
      for (int j = 0; j < 2; ++j) {
        const int c = w * 128 + j * 64 + lane;
        async16(A + (size_t)(m0 + (c >> 2)) * K + k0 + kcb * 32 + (c & 3) * 8,
                &As[kcb * 4096 + (w * 128 + j * 64) * 8]);
        async16(Bt + (size_t)(n0 + (c >> 2)) * K + k0 + kcb * 32 + (c & 3) * 8,
                &Bs[kcb * 4096 + (w * 128 + j * 64) * 8]);
      }
    __syncthreads();
#pragma unroll
    for (int kcb = 0; kcb < 2; ++kcb) {
      bf8 af[4], bfr[4];
#pragma unroll
      for (int mt = 0; mt < 4; ++mt)
        af[mt] =
            *(const bf8*)&As[kcb * 4096 + (wm + mt * 16 + l15) * 32 + q * 8];
#pragma unroll
      for (int nt = 0; nt < 4; ++nt)
        bfr[nt] =
            *(const bf8*)&Bs[kcb * 4096 + (wn + nt * 16 + l15) * 32 + q * 8];
#pragma unroll
      for (int mt = 0; mt < 4; ++mt)
#pragma unroll
        for (int nt = 0; nt < 4; ++nt)
          acc[mt][nt] = __builtin_amdgcn_mfma_f32_16x16x32_bf16(
              af[mt], bfr[nt], acc[mt][nt], 0, 0, 0);
    }
    __syncthreads();
  }
#pragma unroll
  for (int mt = 0; mt < 4; ++mt)
#pragma unroll
    for (int nt = 0; nt < 4; ++nt) {
      const int col = n0 + wn + nt * 16 + l15;
      const float bcol = bias[col];
#pragma unroll
      for (int rg = 0; rg < 4; ++rg) {
        const int row = m0 + wm + mt * 16 + q * 4 + rg;
        Cb[(size_t)row * N + col] = f2bf(fast_tanh(acc[mt][nt][rg] + bcol));
      }
    }
}

// 64x64 tile, BK=64; rows<4096 -> z_s, rows>=4096 -> z_e (both f32)
__global__ __launch_bounds__(256) void gemm64_enc2(
    const short* __restrict__ A, const short* __restrict__ Bt,
    const float* __restrict__ bias, float* __restrict__ Zs,
    float* __restrict__ Ze, int M, int N, int K) {
  __shared__ __align__(16) short As[2 * 64 * 32];
  __shared__ __align__(16) short Bs[2 * 64 * 32];
  const int tid = threadIdx.x;
  const int w = tid >> 6, lane = tid & 63, q = lane >> 4, l15 = lane & 15;
  const int wm = (w >> 1) * 32, wn = (w & 1) * 32;
  const int m0 = blockIdx.y * 64, n0 = blockIdx.x * 64;
  const f32x4 fzero = {0.0f, 0.0f, 0.0f, 0.0f};
  f32x4 acc[2][2];
#pragma unroll
  for (int mt = 0; mt < 2; ++mt)
#pragma unroll
    for (int nt = 0; nt < 2; ++nt) acc[mt][nt] = fzero;

  for (int k0 = 0; k0 < K; k0 += 64) {
    const int c = w * 64 + lane;
#pragma unroll
    for (int kcb = 0; kcb < 2; ++kcb) {
      async16(A + (size_t)(m0 + (c >> 2)) * K + k0 + kcb * 32 + (c & 3) * 8,
              &As[kcb * 2048 + (w * 64) * 8]);
      async16(Bt + (size_t)(n0 + (c >> 2)) * K + k0 + kcb * 32 + (c & 3) * 8,
              &Bs[kcb * 2048 + (w * 64) * 8]);
    }
    __syncthreads();
#pragma unroll
    for (int kcb = 0; kcb < 2; ++kcb) {
      bf8 af[2], bfr[2];
#pragma unroll
      for (int mt = 0; mt < 2; ++mt)
        af[mt] =
            *(const bf8*)&As[kcb * 2048 + (wm + mt * 16 + l15) * 32 + q * 8];
#pragma unroll
      for (int nt = 0; nt < 2; ++nt)
        bfr[nt] =
            *(const bf8*)&Bs[kcb * 2048 + (wn + nt * 16 + l15) * 32 + q * 8];
#pragma unroll
      for (int mt = 0; mt < 2; ++mt)
#pragma unroll
        for (int nt = 0; nt < 2; ++nt)
          acc[mt][nt] = __builtin_amdgcn_mfma_f32_16x16x32_bf16(
              af[mt], bfr[nt], acc[mt][nt], 0, 0, 0);
    }
    __syncthreads();
  }
#pragma unroll
  for (int mt = 0; mt < 2; ++mt)
#pragma unroll
    for (int nt = 0; nt < 2; ++nt) {
      const int col = n0 + wn + nt * 16 + l15;
      const float bcol = bias[col];
#pragma unroll
      for (int rg = 0; rg < 4; ++rg) {
        const int row = m0 + wm + mt * 16 + q * 4 + rg;
        const float val = acc[mt][nt][rg] + bcol;
        if (row < 4096)
          Zs[(size_t)row * N + col] = val;
        else
          Ze[(size_t)(row - 4096) * N + col] = val;
      }
    }
}

// ---------------- fused wind + fallback + trace ----------------
// 512 blocks x 512 threads; block owns 8 REAL rows (rows 8..15 of the MFMA
// M-dim are zero padding; pad lanes q>=2 zeroed at init, stay zero — both
// matmuls are row-independent so padding never contaminates real rows).
// 2 blocks/CU: staggered blocks hide each other's barrier drains.

__global__ __launch_bounds__(512, 2) void trace_fused(
    const float* __restrict__ Xg, const float* __restrict__ ZEg,
    const float* __restrict__ NZg, const short* __restrict__ WT,
    const short* __restrict__ Wp1s, const short* __restrict__ Ww1T,
    const short* __restrict__ Ww2T, const float* __restrict__ bw1,
    const float* __restrict__ bw2, const float* __restrict__ bp1,
    float* __restrict__ out) {
  constexpr float hs = H_STEP;
  __shared__ __align__(16) short XsL[4096];
  __shared__ __align__(16) short UL[4096];
  __shared__ __align__(16) float gvb[2][16];
  __shared__ __align__(16) float vvb[2][16];
  __shared__ __align__(16) float db[2][16];
  const int tid = threadIdx.x;
  const int w = tid >> 6, lane = tid & 63, q = lane >> 4, l15 = lane & 15;
  const int r0 = blockIdx.x * 8, rb = q * 4;
  const float valid = (q < 2) ? 1.0f : 0.0f;  // rows 8..15 are padding

  if (tid < 16) {
    gvb[0][tid] = 0.0f; gvb[1][tid] = 0.0f;
    vvb[0][tid] = 0.0f; vvb[1][tid] = 0.0f;
    db[0][tid] = 0.0f;  db[1][tid] = 0.0f;
  }

  int cc[2], wadr[2][4], radr[8];
  float bp1c[2], bw1c[2], bw2c[2];
#pragma unroll
  for (int t = 0; t < 2; ++t) {
    const int c = w * 32 + t * 16 + l15;
    cc[t] = c;
    const int kc = c >> 3, cx = kc & 15, cl = c & 7;
#pragma unroll
    for (int rg = 0; rg < 4; ++rg)
      wadr[t][rg] = kc * 128 + ((rb + rg) ^ cx) * 8 + cl;
    bp1c[t] = bp1[c];
    bw1c[t] = bw1[c];
    bw2c[t] = bw2[c];
  }
#pragma unroll
  for (int ks = 0; ks < 8; ++ks) {
    const int kq = ks * 4 + q;
    radr[ks] = (kq * 16 + (l15 ^ (kq & 15))) * 8;
  }
  float x[2][4], ze[2][4], nz[2][4];
#pragma unroll
  for (int t = 0; t < 2; ++t)
#pragma unroll
    for (int rg = 0; rg < 4; ++rg) {
      // pad lanes read their block's own rows (in-bounds), then zero out
      const size_t off = (size_t)(r0 + ((rb + rg) & 7)) * 256 + cc[t];
      x[t][rg] = Xg[off] * valid;
      ze[t][rg] = ZEg[off] * valid;
      nz[t][rg] = NZg[off] * valid;
    }
  const f32x4 fzero = {0.0f, 0.0f, 0.0f, 0.0f};

  // ---- wind MLP + degenerate-wind fallback ----
  float v[2][4];
  {
    bf8 Wf1[2][8], Wf2[2][8];
#pragma unroll
    for (int t = 0; t < 2; ++t)
#pragma unroll
      for (int ks = 0; ks < 8; ++ks) {
        Wf1[t][ks] = *(const bf8*)(Ww1T + cc[t] * 256 + ks * 32 + q * 8);
        Wf2[t][ks] = *(const bf8*)(Ww2T + cc[t] * 256 + ks * 32 + q * 8);
      }
#pragma unroll
    for (int t = 0; t < 2; ++t)
#pragma unroll
      for (int rg = 0; rg < 4; ++rg) XsL[wadr[t][rg]] = f2bf(x[t][rg]);
    __syncthreads();
    bf8 af[8];
#pragma unroll
    for (int ks = 0; ks < 8; ++ks) af[ks] = *(const bf8*)&XsL[radr[ks]];
    f32x4 acc[2];
#pragma unroll
    for (int t = 0; t < 2; ++t) {
      f32x4 a0 = fzero, a1 = fzero;
#pragma unroll
      for (int ks = 0; ks < 8; ks += 2) {
        a0 = __builtin_amdgcn_mfma_f32_16x16x32_bf16(af[ks], Wf1[t][ks], a0,
                                                     0, 0, 0);
        a1 = __builtin_amdgcn_mfma_f32_16x16x32_bf16(af[ks + 1],
                                                     Wf1[t][ks + 1], a1, 0, 0,
                                                     0);
      }
      acc[t] = a0 + a1;
    }
#pragma unroll
    for (int t = 0; t < 2; ++t)
#pragma unroll
      for (int rg = 0; rg < 4; ++rg)
        UL[wadr[t][rg]] = f2bf(fast_tanh(acc[t][rg] + bw1c[t]));
    __syncthreads();
#pragma unroll
    for (int ks = 0; ks < 8; ++ks) af[ks] = *(const bf8*)&UL[radr[ks]];
#pragma unroll
    for (int t = 0; t < 2; ++t) {
      f32x4 a0 = fzero, a1 = fzero;
#pragma unroll
      for (int ks = 0; ks < 8; ks += 2) {
        a0 = __builtin_amdgcn_mfma_f32_16x16x32_bf16(af[ks], Wf2[t][ks], a0,
                                                     0, 0, 0);
        a1 = __builtin_amdgcn_mfma_f32_16x16x32_bf16(af[ks + 1],
                                                     Wf2[t][ks + 1], a1, 0, 0,
                                                     0);
      }
      acc[t] = a0 + a1;
#pragma unroll
      for (int rg = 0; rg < 4; ++rg) v[t][rg] = acc[t][rg] + bw2c[t];
    }
    float pn[4], pm[4];
#pragma unroll
    for (int rg = 0; rg < 4; ++rg) {
      pn[rg] = red16(v[0][rg] * v[0][rg] + v[1][rg] * v[1][rg]);
      pm[rg] = red16(nz[0][rg] * nz[0][rg] + nz[1][rg] * nz[1][rg]);
    }
    if (l15 == 0 && q < 2) {
#pragma unroll
      for (int rg = 0; rg < 4; ++rg) {
        atomicAdd(&gvb[0][rb + rg], pn[rg]);
        atomicAdd(&vvb[0][rb + rg], pm[rg]);
      }
    }
    __syncthreads();
#pragma unroll
    for (int rg = 0; rg < 4; ++rg) {
      const float wn = sqrtf(gvb[0][rb + rg] + 1e-24f);
      const float sc = (wn < 1e-5f)
                           ? 1e-4f / (sqrtf(vvb[0][rb + rg] + 1e-24f) + 1e-12f)
                           : 0.0f;
      v[0][rg] = fmaf(sc, nz[0][rg], v[0][rg]) * valid;
      v[1][rg] = fmaf(sc, nz[1][rg], v[1][rg]) * valid;
    }
    __syncthreads();
    if (tid < 16) {
      gvb[0][tid] = 0.0f;
      vvb[0][tid] = 0.0f;
    }
  }

  // ---- trace weight frags (Wf regs dead, reused by allocator) ----
  bf8 B1f[2][8], B2f[2][8];
#pragma unroll
  for (int t = 0; t < 2; ++t)
#pragma unroll
    for (int ks = 0; ks < 8; ++ks) {
      B1f[t][ks] = *(const bf8*)(WT + cc[t] * 256 + ks * 32 + q * 8);
      B2f[t][ks] = *(const bf8*)(Wp1s + cc[t] * 256 + ks * 32 + q * 8);
    }
  float ap[2][4], xacc[2][4], vacc[2][4], md[4];
#pragma unroll
  for (int rg = 0; rg < 4; ++rg) {
    ap[0][rg] = 0.0f; ap[1][rg] = 0.0f;
    xacc[0][rg] = 0.0f; xacc[1][rg] = 0.0f;
    vacc[0][rg] = 0.0f; vacc[1][rg] = 0.0f;
    md[rg] = 3.4e38f;
  }
  const float cxv_t[4] = {0.0f, 0.5f * hs, 0.5f * hs, hs};
  const float cxa_t[4] = {0.0f, 0.0f, 0.25f * hs * hs, 0.5f * hs * hs};
  const float cva_t[4] = {0.0f, 0.5f * hs, 0.5f * hs, hs};

#pragma unroll 1
  for (int step = 0; step < 15; ++step) {
#pragma unroll
    for (int st = 0; st < 4; ++st) {
      const int p = st & 1;
      const float cxv = cxv_t[st], cxa = cxa_t[st], cva = cva_t[st];
      // 1. stage position -> LDS (pad rows stay exactly 0)
#pragma unroll
      for (int t = 0; t < 2; ++t)
#pragma unroll
        for (int rg = 0; rg < 4; ++rg)
          XsL[wadr[t][rg]] =
              f2bf(x[t][rg] + cxv * v[t][rg] + cxa * ap[t][rg]);
      __syncthreads();
      // 2. matmul1: H = Xs @ Wp1
      bf8 af[8];
#pragma unroll
      for (int ks = 0; ks < 8; ++ks) af[ks] = *(const bf8*)&XsL[radr[ks]];
      f32x4 acc[2];
#pragma unroll
      for (int t = 0; t < 2; ++t) {
        f32x4 a0 = fzero, a1 = fzero;
#pragma unroll
        for (int ks = 0; ks < 8; ks += 2) {
          a0 = __builtin_amdgcn_mfma_f32_16x16x32_bf16(af[ks], B1f[t][ks], a0,
                                                       0, 0, 0);
          a1 = __builtin_amdgcn_mfma_f32_16x16x32_bf16(af[ks + 1],
                                                       B1f[t][ks + 1], a1, 0,
                                                       0, 0);
        }
        acc[t] = a0 + a1;
      }
      // U = sech^2 (wp2 absorbed into Wp1s) -> LDS; zero next parity bufs
#pragma unroll
      for (int t = 0; t < 2; ++t)
#pragma unroll
        for (int rg = 0; rg < 4; ++rg)
          UL[wadr[t][rg]] = f2bf(sech2(acc[t][rg] + bp1c[t]) * valid);
      if (tid < 16) {
        gvb[p ^ 1][tid] = 0.0f;
        vvb[p ^ 1][tid] = 0.0f;
      }
      __syncthreads();
      // 3. matmul2: G = U @ (wp2*Wp1)^T
#pragma unroll
      for (int ks = 0; ks < 8; ++ks) af[ks] = *(const bf8*)&UL[radr[ks]];
#pragma unroll
      for (int t = 0; t < 2; ++t) {
        f32x4 a0 = fzero, a1 = fzero;
#pragma unroll
        for (int ks = 0; ks < 8; ks += 2) {
          a0 = __builtin_amdgcn_mfma_f32_16x16x32_bf16(af[ks], B2f[t][ks], a0,
                                                       0, 0, 0);
          a1 = __builtin_amdgcn_mfma_f32_16x16x32_bf16(af[ks + 1],
                                                       B2f[t][ks + 1], a1, 0,
                                                       0, 0);
        }
        acc[t] = a0 + a1;
      }
      // row reductions (real rows only)
      float vs[2][4], pg[4], pv[4];
#pragma unroll
      for (int rg = 0; rg < 4; ++rg) {
        vs[0][rg] = fmaf(cva, ap[0][rg], v[0][rg]);
        vs[1][rg] = fmaf(cva, ap[1][rg], v[1][rg]);
        pg[rg] = red16(fmaf(acc[0][rg], vs[0][rg], acc[1][rg] * vs[1][rg]));
        pv[rg] = red16(fmaf(vs[0][rg], vs[0][rg], vs[1][rg] * vs[1][rg]));
      }
      if (l15 == 0 && q < 2) {
#pragma unroll
        for (int rg = 0; rg < 4; ++rg) {
          atomicAdd(&gvb[p][rb + rg], pg[rg]);
          atomicAdd(&vvb[p][rb + rg], pv[rg]);
        }
      }
      __syncthreads();
      // 4. broadcast read + accel + RK4 accumulation (pad rows read zeros)
      const f32x4 gv4 = *(const f32x4*)&gvb[p][rb];
      const f32x4 vv4 = *(const f32x4*)&vvb[p][rb];
#pragma unroll
      for (int t = 0; t < 2; ++t)
#pragma unroll
        for (int rg = 0; rg < 4; ++rg) {
          const float a = -gv4[rg] * vs[t][rg] + 0.5f * vv4[rg] * acc[t][rg];
          ap[t][rg] = a;
          if (st == 0) {
            xacc[t][rg] = a;
            vacc[t][rg] = a;
          } else if (st < 3) {
            xacc[t][rg] += a;
            vacc[t][rg] += 2.0f * a;
          } else {
            vacc[t][rg] += a;
          }
        }
      // 5. st3: step update + closest approach
      if (st == 3) {
        const int sp = step & 1;
        float pd[4];
#pragma unroll
        for (int rg = 0; rg < 4; ++rg) {
          float acc_d = 0.0f;
#pragma unroll
          for (int t = 0; t < 2; ++t) {
            const float xn =
                x[t][rg] + hs * v[t][rg] + (hs * hs / 6.0f) * xacc[t][rg];
            const float vn = v[t][rg] + (hs / 6.0f) * vacc[t][rg];
            x[t][rg] = xn;
            v[t][rg] = vn;
            const float d = xn - ze[t][rg];
            acc_d = fmaf(d, d, acc_d);
          }
          pd[rg] = red16(acc_d);
        }
        if (l15 == 0 && q < 2) {
#pragma unroll
          for (int rg = 0; rg < 4; ++rg) atomicAdd(&db[sp][rb + rg], pd[rg]);
        }
        if (tid < 16) db[sp ^ 1][tid] = 0.0f;
        __syncthreads();
        const f32x4 d4 = *(const f32x4*)&db[sp][rb];
#pragma unroll
        for (int rg = 0; rg < 4; ++rg) md[rg] = fminf(md[rg], d4[rg]);
      }
    }
  }
  if (w == 0 && l15 == 0 && q < 2)  // q=0,1 cover the 8 real rows
    atomicAdd(out, (md[0] + md[1] + md[2] + md[3]) * (1.0f / 4096.0f));
}

}  // namespace

extern "C" void kernel_launch(void* const* d_in, const int* in_sizes, int n_in,
                              void* d_out, int out_size, void* d_ws,
                              size_t ws_size, hipStream_t stream) {
  (void)in_sizes; (void)n_in; (void)out_size; (void)ws_size;
  const float* x_start = (const float*)d_in[0];
  const float* x_end = (const float*)d_in[1];
  const float* noise = (const float*)d_in[2];
  const float* W1 = (const float*)d_in[3];
  const float* b1 = (const float*)d_in[4];
  const float* W2 = (const float*)d_in[5];
  const float* b2 = (const float*)d_in[6];
  const float* Ww1 = (const float*)d_in[7];
  const float* bw1 = (const float*)d_in[8];
  const float* Ww2 = (const float*)d_in[9];
  const float* bw2 = (const float*)d_in[10];
  const float* Wp1 = (const float*)d_in[11];
  const float* bp1 = (const float*)d_in[12];
  const float* wp2 = (const float*)d_in[13];
  float* out = (float*)d_out;

  // workspace layout (~61 MB)
  float* Xf = (float*)d_ws;                        // z_s  4096*256 f32
  float* ZEf = Xf + (size_t)4096 * 256;            // z_e
  short* XSb = (short*)(ZEf + (size_t)4096 * 256); // x bf16 8192*2048
  short* H1b = XSb + (size_t)8192 * 2048;          // enc hidden bf16 8192*1024
  short* W1T = H1b + (size_t)8192 * 1024;          // 1024*2048
  short* W2T = W1T + (size_t)1024 * 2048;          // 256*1024
  short* Ww1T = W2T + (size_t)256 * 1024;
  short* Ww2T = Ww1T + 65536;
  short* WpT = Ww2T + 65536;                       // Wp1^T
  short* Wp1s = WpT + 65536;                       // wp2-scaled Wp1 row-major

  const dim3 blk(256);

  prep_all<<<4608, blk, 0, stream>>>(x_start, x_end, W1, W2, Ww1, Ww2, Wp1,
                                     wp2, XSb, W1T, W2T, Ww1T, Ww2T, WpT,
                                     Wp1s);
  gemm128_tanh<<<dim3(8, 64), blk, 0, stream>>>(XSb, W1T, b1, H1b, 8192, 1024,
                                                2048);
  gemm64_enc2<<<dim3(4, 128), blk, 0, stream>>>(H1b, W2T, b2, Xf, ZEf, 8192,
                                                256, 1024);
  hipMemsetAsync(d_out, 0, sizeof(float), stream);
  trace_fused<<<512, dim3(512), 0, stream>>>(Xf, ZEf, noise, WpT, Wp1s, Ww1T,
                                             Ww2T, bw1, bw2, bp1, out);
}